// Round 1
// baseline (312.054 us; speedup 1.0000x reference)
//
#include <hip/hip_runtime.h>
#include <hip/hip_bf16.h>
#include <hip/hip_cooperative_groups.h>
#include <cstdint>
#include <cstddef>

namespace cg = cooperative_groups;

typedef __bf16 bf16_t;
typedef bf16_t bf16x8 __attribute__((ext_vector_type(8)));
typedef float f32x4 __attribute__((ext_vector_type(4)));

#define BN_EPS 1e-5f

// r7 lesson: per-lane GLOBAL addresses for global_load_lds must stay
// lane-order contiguous within 128B lines (request merging); LDS swizzles only
// on explicit ds_write paths.
// r8 lesson: __threadfence() is an L2-writeback-class op on gfx950 — never in
// a per-block epilogue. Cross-block handoff: dispatch boundary or grid.sync().
// r10 lesson: hipLaunchCooperativeKernel can reject the launch silently at
// exactly-full LDS occupancy — validate with host-side occupancy query and
// keep a fallback path.
// r11 change: kill the stage->drain->compute serialization (MfmaUtil was 14%
// with 86% stall). GEMM2: double-buffered LDS, prefetch next K-tile before
// computing current, ONE __syncthreads per K-step (T3 minimum-2-phase).
// GEMM1: B-panel is L2-resident (512 KB) -> load B fragments straight into
// registers, deleting all main-loop barriers; waves run free.
__device__ __forceinline__ void async_load16(const bf16_t* g, bf16_t* lds) {
  __builtin_amdgcn_global_load_lds(
      (__attribute__((address_space(1))) uint32_t*)(g),
      (__attribute__((address_space(3))) uint32_t*)(lds),
      16, 0, 0);
}

// ---- Weight prep (transposes + BN folds), tiny ------------------------------
__global__ void prep_weights_kernel(const float* __restrict__ W1, const float* __restrict__ W2,
                                    const float* b1, const float* g1, const float* be1,
                                    const float* m1, const float* v1,
                                    const float* b2, const float* g2, const float* be2,
                                    const float* m2, const float* v2,
                                    bf16_t* __restrict__ W1T, bf16_t* __restrict__ W2T,
                                    float* s1, float* t1, float* s2, float* t2,
                                    float* w1last) {
  const int b = blockIdx.x;
  if (b < 192) {
    const float* src;
    bf16_t* dst;
    int R, C, bx, by;
    if (b < 64) { src = W1; dst = W1T; R = 256; C = 1024; bx = b & 15; by = b >> 4; }
    else        { src = W2; dst = W2T; R = 1024; C = 512; bx = (b - 64) & 7; by = (b - 64) >> 3; }
    __shared__ bf16_t tile[64][66];
    const int r0 = by * 64, c0 = bx * 64;
    const int tc = threadIdx.x & 63;
    const int tr4 = threadIdx.x >> 6;
#pragma unroll
    for (int i = 0; i < 16; ++i) {
      int r = i * 4 + tr4;
      tile[r][tc] = (bf16_t)src[(size_t)(r0 + r) * C + c0 + tc];  // coalesced read
    }
    __syncthreads();
#pragma unroll
    for (int i = 0; i < 16; ++i) {
      int rr = i * 4 + tr4;
      dst[(size_t)(c0 + rr) * R + r0 + tc] = tile[tc][rr];  // coalesced write
    }
  } else {
    for (int i = threadIdx.x; i < 1024; i += 256) {
      float s = g1[i] * rsqrtf(v1[i] + BN_EPS);
      s1[i] = s;
      t1[i] = be1[i] - m1[i] * s + b1[i] * s;  // bn(z+b1) = z*s + t
      w1last[i] = W1[256 * 1024 + i];          // conv-feature row (coalesced)
      if (i < 512) {
        float s2v = g2[i] * rsqrtf(v2[i] + BN_EPS);
        s2[i] = s2v;
        t2[i] = be2[i] - m2[i] * s2v + b2[i] * s2v;
      }
    }
  }
}

// ---- gemm1 body: A-resident in LDS, B fragments register-direct from L2 -----
// 128 rows/tile. As = 64 KB (chunk-swizzled) + convs 512 B. No main-loop
// barriers: after the prologue sync, each wave runs its 4 column-chunks fully
// independently; the unrolled K-loop gives the compiler counted-vmcnt register
// loads to pipeline.
__device__ __forceinline__ void gemm1_body(
    const float* __restrict__ x, const bf16_t* __restrict__ W1T,
    const float* __restrict__ s1, const float* __restrict__ t1,
    const float* __restrict__ w1last, bf16_t* __restrict__ h1,
    unsigned char* smem, int mTile, int lane, int w) {
  bf16_t* As = (bf16_t*)smem;               // [128][256], chunk-swizzled
  float* convs = (float*)(smem + 65536);    // [128] floats (own space now)
  const int l15 = lane & 15;
  const int quad = lane >> 4;
  const int p = w >> 1;        // wave pair 0..1
  const int h = w & 1;         // row-half within pair

  // Prologue: read x fp32, cast->bf16 into As (swizzled), per-row conv.
  {
    const int rsub = lane >> 5;     // 0..1
    const int c = lane & 31;        // 8-elem chunk within row
#pragma unroll
    for (int i = 0; i < 16; ++i) {
      int row = w * 32 + i * 2 + rsub;
      const float* gx = x + (size_t)(mTile + row) * 256 + c * 8;
      const float4 a = *(const float4*)gx;
      const float4 bq = *(const float4*)(gx + 4);
      float s = a.x + a.y + a.z + a.w + bq.x + bq.y + bq.z + bq.w;
      bf16x8 v = {(bf16_t)a.x, (bf16_t)a.y, (bf16_t)a.z, (bf16_t)a.w,
                  (bf16_t)bq.x, (bf16_t)bq.y, (bf16_t)bq.z, (bf16_t)bq.w};
      *(bf16x8*)(As + row * 256 + (c ^ (row & 7)) * 8) = v;
#pragma unroll
      for (int m = 1; m <= 16; m <<= 1) s += __shfl_xor(s, m);  // 32-lane groups
      if (c == 0) convs[row] = (s > 0.0f) ? 1.0f : 0.0f;  // mean>0 <=> sum>0
    }
  }
  __syncthreads();  // As + convs visible; the ONLY barrier in gemm1
  float cf[4][4];
#pragma unroll
  for (int ti = 0; ti < 4; ++ti)
#pragma unroll
    for (int r = 0; r < 4; ++r)
      cf[ti][r] = convs[h * 64 + ti * 16 + quad * 4 + r];

  for (int j = 0; j < 4; ++j) {
    const int colbase = (p * 4 + j) * 128;
    f32x4 acc[4][8];
#pragma unroll
    for (int i = 0; i < 4; ++i)
#pragma unroll
      for (int t = 0; t < 8; ++t) {
        f32x4 z = {0.f, 0.f, 0.f, 0.f};
        acc[i][t] = z;
      }

    // Per-lane B fragment base: row (= W1 col) colbase + tj*16 + l15, k chunk
    // quad*8 + ks*32. W1T is 512 KB -> L2-resident; 16 B/lane loads.
    const bf16_t* gB = W1T + (size_t)(colbase + l15) * 256 + quad * 8;

#pragma unroll
    for (int ks = 0; ks < 8; ++ks) {
      bf16x8 bfr[8];
#pragma unroll
      for (int tj = 0; tj < 8; ++tj)
        bfr[tj] = *(const bf16x8*)(gB + (size_t)(tj * 16) * 256 + ks * 32);
      bf16x8 af[4];
#pragma unroll
      for (int ti = 0; ti < 4; ++ti) {
        int row = h * 64 + ti * 16 + l15;
        af[ti] = *(const bf16x8*)(As + row * 256 + ((ks * 4 + quad) ^ (l15 & 7)) * 8);
      }
#pragma unroll
      for (int ti = 0; ti < 4; ++ti)
#pragma unroll
        for (int tj = 0; tj < 8; ++tj)
          acc[ti][tj] = __builtin_amdgcn_mfma_f32_16x16x32_bf16(af[ti], bfr[tj], acc[ti][tj], 0, 0, 0);
    }

    // Per-chunk epilogue: conv rank-1 + BN1 + ReLU -> h1 (bf16)
    float sc[8], tc[8], wl[8];
#pragma unroll
    for (int tj = 0; tj < 8; ++tj) {
      int c = colbase + tj * 16 + l15;
      sc[tj] = s1[c];
      tc[tj] = t1[c];
      wl[tj] = w1last[c];
    }
#pragma unroll
    for (int ti = 0; ti < 4; ++ti)
#pragma unroll
      for (int r = 0; r < 4; ++r) {
        int row = mTile + h * 64 + ti * 16 + quad * 4 + r;
        size_t base = (size_t)row * 1024 + colbase;
#pragma unroll
        for (int tj = 0; tj < 8; ++tj) {
          float z = acc[ti][tj][r] + cf[ti][r] * wl[tj];
          z = fmaxf(z * sc[tj] + tc[tj], 0.f);
          h1[base + tj * 16 + l15] = (bf16_t)z;
        }
      }
  }
}

// ---- gemm2 task body: one 256x128 tile -> per-N partials --------------------
// Double-buffered LDS (As2 2x16 KB + Bs2 2x8 KB = 48 KB). Minimum-2-phase
// pipeline: issue next K-tile's global_load_lds BEFORE computing the current
// tile; ONE __syncthreads (vmcnt(0)+lgkmcnt(0)+barrier) per K-step. Staging
// of tile t+1 hides under MFMA of tile t. Plain stores, no atomics/fences.
__device__ __forceinline__ void gemm2_task_body(
    const bf16_t* __restrict__ h1, const bf16_t* __restrict__ W2T,
    const float* __restrict__ s2, const float* __restrict__ t2,
    const float* __restrict__ W3, float* __restrict__ partials,
    unsigned char* smem, int task, int lane, int w) {
  bf16_t* As2 = (bf16_t*)smem;             // [2][256][32]
  bf16_t* Bs2 = (bf16_t*)(smem + 32768);   // [2][128][32]
  const int l15 = lane & 15;
  const int quad = lane >> 4;
  const int sRow = lane >> 2;
  const int sCol = (lane & 3) * 8;

  const int mt = (task >> 5) * 8 + (task & 7);   // XCD-grouped M-tile
  const int mTile2 = mt * 256;
  const int nt = (task >> 3) & 3;
  const int nTile = nt * 128;

  const bf16_t* gA = h1 + (size_t)(mTile2 + w * 64 + sRow) * 1024 + sCol;
  const bf16_t* gB = W2T + (size_t)(nTile + w * 32 + sRow) * 1024 + sCol;
  bf16_t* lA0 = As2 + (w * 64) * 32;
  bf16_t* lB0 = Bs2 + (w * 32) * 32;

  f32x4 acc[4][8];
#pragma unroll
  for (int i = 0; i < 4; ++i)
#pragma unroll
    for (int j = 0; j < 8; ++j) {
      f32x4 z = {0.f, 0.f, 0.f, 0.f};
      acc[i][j] = z;
    }

  // Protect LDS against the previous task's (or gemm1's) in-flight readers.
  __syncthreads();

#define STAGE2(buf, k0)                                                     \
  do {                                                                      \
    bf16_t* lA = lA0 + (buf)*8192;                                          \
    bf16_t* lB = lB0 + (buf)*4096;                                          \
    async_load16(gA + (k0), lA);                                            \
    async_load16(gA + (size_t)16 * 1024 + (k0), lA + 16 * 32);              \
    async_load16(gA + (size_t)32 * 1024 + (k0), lA + 32 * 32);              \
    async_load16(gA + (size_t)48 * 1024 + (k0), lA + 48 * 32);              \
    async_load16(gB + (k0), lB);                                            \
    async_load16(gB + (size_t)16 * 1024 + (k0), lB + 16 * 32);              \
  } while (0)

  STAGE2(0, 0);
  __syncthreads();  // prologue drain (vmcnt(0)) + barrier

  int buf = 0;
  for (int k0 = 0; k0 < 1024; k0 += 32) {
    if (k0 + 32 < 1024) STAGE2(buf ^ 1, k0 + 32);  // prefetch next K-tile

    bf16x8 af[4], bfr[8];
#pragma unroll
    for (int t = 0; t < 4; ++t)
      af[t] = *(const bf16x8*)(As2 + buf * 8192 + (w * 64 + t * 16 + l15) * 32 + quad * 8);
#pragma unroll
    for (int t = 0; t < 8; ++t)
      bfr[t] = *(const bf16x8*)(Bs2 + buf * 4096 + (t * 16 + l15) * 32 + quad * 8);
#pragma unroll
    for (int ti = 0; ti < 4; ++ti)
#pragma unroll
      for (int tj = 0; tj < 8; ++tj)
        acc[ti][tj] = __builtin_amdgcn_mfma_f32_16x16x32_bf16(af[ti], bfr[tj], acc[ti][tj], 0, 0, 0);

    if (k0 + 32 < 1024) {
      __syncthreads();  // drains this step's stage (vmcnt) + our ds_reads (lgkm)
      buf ^= 1;
    }
  }
#undef STAGE2

  float sc[8], tc[8], w3c[8];
#pragma unroll
  for (int tj = 0; tj < 8; ++tj) {
    int c = nTile + tj * 16 + l15;
    sc[tj] = s2[c];
    tc[tj] = t2[c];
    w3c[tj] = W3[c];
  }
#pragma unroll
  for (int ti = 0; ti < 4; ++ti)
#pragma unroll
    for (int r = 0; r < 4; ++r) {
      float pv = 0.f;
#pragma unroll
      for (int tj = 0; tj < 8; ++tj) {
        float z = fmaxf(acc[ti][tj][r] * sc[tj] + tc[tj], 0.f);
        pv += z * w3c[tj];
      }
#pragma unroll
      for (int m = 1; m <= 8; m <<= 1) pv += __shfl_xor(pv, m);
      if (l15 == 0)
        partials[(size_t)nt * 65536 + mTile2 + w * 64 + ti * 16 + quad * 4 + r] = pv;
    }
}

// ---- Standalone wrappers (fallback path) ------------------------------------
__global__ __launch_bounds__(256, 2) void gemm1_kernel(
    const float* __restrict__ x, const bf16_t* __restrict__ W1T,
    const float* __restrict__ s1, const float* __restrict__ t1,
    const float* __restrict__ w1last, bf16_t* __restrict__ h1) {
  __shared__ __align__(16) unsigned char smem[66048];
  gemm1_body(x, W1T, s1, t1, w1last, h1, smem, blockIdx.x * 128,
             threadIdx.x & 63, threadIdx.x >> 6);
}

__global__ __launch_bounds__(256, 2) void gemm2_kernel(
    const bf16_t* __restrict__ h1, const bf16_t* __restrict__ W2T,
    const float* __restrict__ s2, const float* __restrict__ t2,
    const float* __restrict__ W3, float* __restrict__ partials) {
  __shared__ __align__(16) unsigned char smem[49152];
  gemm2_task_body(h1, W2T, s2, t2, W3, partials, smem, blockIdx.x,
                  threadIdx.x & 63, threadIdx.x >> 6);
}

__global__ void sigmoid_partials_kernel(const float* __restrict__ partials,
                                        const float* __restrict__ b3,
                                        float* __restrict__ out) {
  int i = blockIdx.x * 256 + threadIdx.x;
  float z = partials[i] + partials[65536 + i] + partials[2 * 65536 + i] +
            partials[3 * 65536 + i] + b3[0];
  out[i] = 1.0f / (1.0f + expf(-z));
}

// ---- Cooperative fused path -------------------------------------------------
__global__ __launch_bounds__(256, 2) void fused_mlp_coop(
    const float* __restrict__ x,
    const bf16_t* __restrict__ W1T, const bf16_t* __restrict__ W2T,
    const float* __restrict__ s1, const float* __restrict__ t1,
    const float* __restrict__ w1last,
    const float* __restrict__ s2, const float* __restrict__ t2,
    const float* __restrict__ W3, const float* __restrict__ b3,
    bf16_t* __restrict__ h1, float* __restrict__ partials,
    float* __restrict__ out) {
  __shared__ __align__(16) unsigned char smem[66048];
  cg::grid_group grid = cg::this_grid();
  const int tid = threadIdx.x;
  const int lane = tid & 63;
  const int w = tid >> 6;

  gemm1_body(x, W1T, s1, t1, w1last, h1, smem, blockIdx.x * 128, lane, w);

  grid.sync();  // h1 visible grid-wide (also block-syncs LDS handoff)

  gemm2_task_body(h1, W2T, s2, t2, W3, partials, smem, blockIdx.x, lane, w);
  gemm2_task_body(h1, W2T, s2, t2, W3, partials, smem, blockIdx.x + 512, lane, w);

  grid.sync();  // partials visible

  if (tid < 128) {
    int r = blockIdx.x * 128 + tid;
    float z = partials[r] + partials[65536 + r] + partials[2 * 65536 + r] +
              partials[3 * 65536 + r] + b3[0];
    out[r] = 1.0f / (1.0f + expf(-z));
  }
}

extern "C" void kernel_launch(void* const* d_in, const int* in_sizes, int n_in,
                              void* d_out, int out_size, void* d_ws, size_t ws_size,
                              hipStream_t stream) {
  const float* x = (const float*)d_in[0];
  const float* W1 = (const float*)d_in[1];
  const float* b1 = (const float*)d_in[2];
  const float* g1 = (const float*)d_in[3];
  const float* be1 = (const float*)d_in[4];
  const float* m1 = (const float*)d_in[5];
  const float* v1 = (const float*)d_in[6];
  const float* W2 = (const float*)d_in[7];
  const float* b2 = (const float*)d_in[8];
  const float* g2 = (const float*)d_in[9];
  const float* be2 = (const float*)d_in[10];
  const float* m2 = (const float*)d_in[11];
  const float* v2 = (const float*)d_in[12];
  const float* W3 = (const float*)d_in[13];
  const float* b3 = (const float*)d_in[14];
  float* out = (float*)d_out;

  char* p = (char*)d_ws;
  bf16_t* h1 = (bf16_t*)p;       p += (size_t)65536 * 1024 * 2;  // 128 MB
  float* partials = (float*)p;   p += (size_t)4 * 65536 * 4;     // 1 MB
  bf16_t* W1T = (bf16_t*)p;      p += (size_t)1024 * 256 * 2;
  bf16_t* W2T = (bf16_t*)p;      p += (size_t)512 * 1024 * 2;
  float* w1last = (float*)p;     p += 1024 * 4;
  float* s1 = (float*)p;         p += 1024 * 4;
  float* t1 = (float*)p;         p += 1024 * 4;
  float* s2 = (float*)p;         p += 512 * 4;
  float* t2 = (float*)p;         p += 512 * 4;

  prep_weights_kernel<<<193, 256, 0, stream>>>(W1, W2, b1, g1, be1, m1, v1,
                                               b2, g2, be2, m2, v2,
                                               W1T, W2T, s1, t1, s2, t2, w1last);

  // Host-side (capture-safe) validation of the cooperative path.
  int dev = 0;
  (void)hipGetDevice(&dev);
  int coopOk = 0;
  (void)hipDeviceGetAttribute(&coopOk, hipDeviceAttributeCooperativeLaunch, dev);
  int numCU = 0;
  (void)hipDeviceGetAttribute(&numCU, hipDeviceAttributeMultiprocessorCount, dev);
  int maxBlk = 0;
  (void)hipOccupancyMaxActiveBlocksPerMultiprocessor(&maxBlk, fused_mlp_coop, 256, 0);

  bool useCoop = (coopOk != 0) && ((long)maxBlk * (long)numCU >= 512L);
  if (useCoop) {
    void* args[] = {(void*)&x, (void*)&W1T, (void*)&W2T, (void*)&s1, (void*)&t1,
                    (void*)&w1last, (void*)&s2, (void*)&t2, (void*)&W3, (void*)&b3,
                    (void*)&h1, (void*)&partials, (void*)&out};
    hipError_t e = hipLaunchCooperativeKernel((const void*)fused_mlp_coop,
                                              dim3(512), dim3(256), args, 0, stream);
    if (e != hipSuccess) useCoop = false;
  }
  if (!useCoop) {
    gemm1_kernel<<<512, 256, 0, stream>>>(x, W1T, s1, t1, w1last, h1);
    gemm2_kernel<<<1024, 256, 0, stream>>>(h1, W2T, s2, t2, W3, partials);
    sigmoid_partials_kernel<<<256, 256, 0, stream>>>(partials, b3, out);
  }
}

// Round 2
// 251.425 us; speedup vs baseline: 1.2411x; 1.2411x over previous
//
#include <hip/hip_runtime.h>
#include <hip/hip_bf16.h>
#include <hip/hip_cooperative_groups.h>
#include <cstdint>
#include <cstddef>

namespace cg = cooperative_groups;

typedef __bf16 bf16_t;
typedef bf16_t bf16x8 __attribute__((ext_vector_type(8)));
typedef float f32x4 __attribute__((ext_vector_type(4)));

#define BN_EPS 1e-5f

// r7 lesson: per-lane GLOBAL addresses for global_load_lds must stay
// lane-order contiguous within 128B lines (request merging); LDS swizzles only
// via pre-swizzled SOURCE addresses (within-line permutes are fine).
// r8 lesson: __threadfence() is an L2-writeback-class op on gfx950 — never in
// a per-block epilogue. Cross-block handoff: dispatch boundary or grid.sync().
// r10 lesson: hipLaunchCooperativeKernel can reject the launch silently at
// exactly-full LDS occupancy — validate with host-side occupancy query and
// keep a fallback path.
// r11 lesson (REGRESSED): register-direct B loads in gemm1 double B traffic
// and expose L2 latency at 2 waves/SIMD. B must be LDS-staged.
// r12 change: gemm1 B staging made WAVE-PRIVATE (4KB region per wave), synced
// by per-wave s_waitcnt vmcnt(0) only — zero barriers in the K-loop, waves
// slip freely. XOR swizzle (phys_chunk = logical ^ ((row>>1)&3)) on gemm1-Bs
// and gemm2-As2/Bs2 kills the 64B-stride bank conflicts. GEMM2 keeps the r11
// double-buffer (1 barrier/K-step). Conv feature carried as a lane bitmask.
__device__ __forceinline__ void async_load16(const bf16_t* g, bf16_t* lds) {
  __builtin_amdgcn_global_load_lds(
      (__attribute__((address_space(1))) uint32_t*)(g),
      (__attribute__((address_space(3))) uint32_t*)(lds),
      16, 0, 0);
}

// ---- Weight prep (transposes + BN folds), tiny ------------------------------
__global__ void prep_weights_kernel(const float* __restrict__ W1, const float* __restrict__ W2,
                                    const float* b1, const float* g1, const float* be1,
                                    const float* m1, const float* v1,
                                    const float* b2, const float* g2, const float* be2,
                                    const float* m2, const float* v2,
                                    bf16_t* __restrict__ W1T, bf16_t* __restrict__ W2T,
                                    float* s1, float* t1, float* s2, float* t2,
                                    float* w1last) {
  const int b = blockIdx.x;
  if (b < 192) {
    const float* src;
    bf16_t* dst;
    int R, C, bx, by;
    if (b < 64) { src = W1; dst = W1T; R = 256; C = 1024; bx = b & 15; by = b >> 4; }
    else        { src = W2; dst = W2T; R = 1024; C = 512; bx = (b - 64) & 7; by = (b - 64) >> 3; }
    __shared__ bf16_t tile[64][66];
    const int r0 = by * 64, c0 = bx * 64;
    const int tc = threadIdx.x & 63;
    const int tr4 = threadIdx.x >> 6;
#pragma unroll
    for (int i = 0; i < 16; ++i) {
      int r = i * 4 + tr4;
      tile[r][tc] = (bf16_t)src[(size_t)(r0 + r) * C + c0 + tc];  // coalesced read
    }
    __syncthreads();
#pragma unroll
    for (int i = 0; i < 16; ++i) {
      int rr = i * 4 + tr4;
      dst[(size_t)(c0 + rr) * R + r0 + tc] = tile[tc][rr];  // coalesced write
    }
  } else {
    for (int i = threadIdx.x; i < 1024; i += 256) {
      float s = g1[i] * rsqrtf(v1[i] + BN_EPS);
      s1[i] = s;
      t1[i] = be1[i] - m1[i] * s + b1[i] * s;  // bn(z+b1) = z*s + t
      w1last[i] = W1[256 * 1024 + i];          // conv-feature row (coalesced)
      if (i < 512) {
        float s2v = g2[i] * rsqrtf(v2[i] + BN_EPS);
        s2[i] = s2v;
        t2[i] = be2[i] - m2[i] * s2v + b2[i] * s2v;
      }
    }
  }
}

// ---- gemm1 body: A-resident in LDS, wave-private swizzled B staging ---------
// 128 rows/tile. As = 64 KB (chunk-swizzled). Bs = 4 waves x 4 KB, each wave
// stages and reads ONLY its own region -> sync is per-wave vmcnt(0), no
// __syncthreads in the K-loop. Wave w owns cols {j*256 + w*64 .. +63}.
__device__ __forceinline__ void gemm1_body(
    const float* __restrict__ x, const bf16_t* __restrict__ W1T,
    const float* __restrict__ s1, const float* __restrict__ t1,
    const float* __restrict__ w1last, bf16_t* __restrict__ h1,
    unsigned char* smem, int mTile, int lane, int w) {
  bf16_t* As = (bf16_t*)smem;               // [128][256], chunk-swizzled
  bf16_t* Bs = (bf16_t*)(smem + 65536);     // [4 waves][64][32], chunk-swizzled
  float* convs = (float*)(smem + 65536);    // transient overlay (pre-staging)
  const int l15 = lane & 15;
  const int quad = lane >> 4;

  // Prologue: read x fp32, cast->bf16 into As (swizzled), per-row conv.
  {
    const int rsub = lane >> 5;     // 0..1
    const int c = lane & 31;        // 8-elem chunk within row
#pragma unroll
    for (int i = 0; i < 16; ++i) {
      int row = w * 32 + i * 2 + rsub;
      const float* gx = x + (size_t)(mTile + row) * 256 + c * 8;
      const float4 a = *(const float4*)gx;
      const float4 bq = *(const float4*)(gx + 4);
      float s = a.x + a.y + a.z + a.w + bq.x + bq.y + bq.z + bq.w;
      bf16x8 v = {(bf16_t)a.x, (bf16_t)a.y, (bf16_t)a.z, (bf16_t)a.w,
                  (bf16_t)bq.x, (bf16_t)bq.y, (bf16_t)bq.z, (bf16_t)bq.w};
      *(bf16x8*)(As + row * 256 + (c ^ (row & 7)) * 8) = v;
#pragma unroll
      for (int m = 1; m <= 16; m <<= 1) s += __shfl_xor(s, m);  // 32-lane groups
      if (c == 0) convs[row] = (s > 0.0f) ? 1.0f : 0.0f;  // mean>0 <=> sum>0
    }
  }
  __syncthreads();  // As + convs visible

  // Conv feature as a per-lane bitmask over the 32 output rows this lane owns.
  unsigned cmask = 0;
#pragma unroll
  for (int ti = 0; ti < 8; ++ti)
#pragma unroll
    for (int r = 0; r < 4; ++r)
      if (convs[ti * 16 + quad * 4 + r] > 0.5f) cmask |= (1u << (ti * 4 + r));
  __syncthreads();  // all convs readers done before Bs staging overwrites it

  bf16_t* BsW = Bs + w * 2048;          // this wave's private 4 KB region
  const int srow = lane >> 2;           // 0..15 (staging row within 16-group)
  // Pre-swizzled source chunk: physical chunk (lane&3) holds logical chunk
  // (lane&3) ^ ((row>>1)&3). Permute stays within one 64B line (r7-safe).
  const int schunk = (lane & 3) ^ ((lane >> 3) & 3);
  const int rchunk = quad ^ ((l15 >> 1) & 3);   // read-side inverse

  for (int j = 0; j < 4; ++j) {
    const int colbase = j * 256 + w * 64;
    f32x4 acc[8][4];
#pragma unroll
    for (int i = 0; i < 8; ++i)
#pragma unroll
      for (int t = 0; t < 4; ++t) {
        f32x4 z = {0.f, 0.f, 0.f, 0.f};
        acc[i][t] = z;
      }

    const bf16_t* gB = W1T + (size_t)(colbase + srow) * 256 + schunk * 8;

    for (int ks = 0; ks < 8; ++ks) {
      // Stage this wave's 64x32 B sub-tile (4 KB) into its private region.
#pragma unroll
      for (int i = 0; i < 4; ++i)
        async_load16(gB + (size_t)(i * 16) * 256 + ks * 32, BsW + i * 512 + lane * 8);
      asm volatile("s_waitcnt vmcnt(0)" ::: "memory");  // per-wave, no barrier

      bf16x8 af[8], bfr[4];
#pragma unroll
      for (int tj = 0; tj < 4; ++tj)
        bfr[tj] = *(const bf16x8*)(BsW + (tj * 16 + l15) * 32 + rchunk * 8);
#pragma unroll
      for (int ti = 0; ti < 8; ++ti)
        af[ti] = *(const bf16x8*)(As + (ti * 16 + l15) * 256 + ((ks * 4 + quad) ^ (l15 & 7)) * 8);
#pragma unroll
      for (int ti = 0; ti < 8; ++ti)
#pragma unroll
        for (int tj = 0; tj < 4; ++tj)
          acc[ti][tj] = __builtin_amdgcn_mfma_f32_16x16x32_bf16(af[ti], bfr[tj], acc[ti][tj], 0, 0, 0);
    }

    // Per-chunk epilogue: conv rank-1 + BN1 + ReLU -> h1 (bf16)
    float sc[4], tcv[4], wl[4];
#pragma unroll
    for (int tj = 0; tj < 4; ++tj) {
      int c = colbase + tj * 16 + l15;
      sc[tj] = s1[c];
      tcv[tj] = t1[c];
      wl[tj] = w1last[c];
    }
#pragma unroll
    for (int ti = 0; ti < 8; ++ti)
#pragma unroll
      for (int r = 0; r < 4; ++r) {
        int row = mTile + ti * 16 + quad * 4 + r;
        size_t base = (size_t)row * 1024 + colbase;
        const float cfv = ((cmask >> (ti * 4 + r)) & 1u) ? 1.0f : 0.0f;
#pragma unroll
        for (int tj = 0; tj < 4; ++tj) {
          float z = acc[ti][tj][r] + cfv * wl[tj];
          z = fmaxf(z * sc[tj] + tcv[tj], 0.f);
          h1[base + tj * 16 + l15] = (bf16_t)z;
        }
      }
  }
}

// ---- gemm2 task body: one 256x128 tile -> per-N partials --------------------
// Double-buffered LDS (As2 2x16 KB + Bs2 2x8 KB = 48 KB), minimum-2-phase:
// prefetch next K-tile before computing current, ONE __syncthreads per K-step.
// As2/Bs2 chunk-swizzled (source-side) to kill 64B-stride bank conflicts.
__device__ __forceinline__ void gemm2_task_body(
    const bf16_t* __restrict__ h1, const bf16_t* __restrict__ W2T,
    const float* __restrict__ s2, const float* __restrict__ t2,
    const float* __restrict__ W3, float* __restrict__ partials,
    unsigned char* smem, int task, int lane, int w) {
  bf16_t* As2 = (bf16_t*)smem;             // [2][256][32] swizzled
  bf16_t* Bs2 = (bf16_t*)(smem + 32768);   // [2][128][32] swizzled
  const int l15 = lane & 15;
  const int quad = lane >> 4;
  const int sRow = lane >> 2;
  const int sColSwz = ((lane & 3) ^ ((lane >> 3) & 3)) * 8;  // pre-swizzled src
  const int rchunk8 = (quad ^ ((l15 >> 1) & 3)) * 8;         // read-side inverse

  const int mt = (task >> 5) * 8 + (task & 7);   // XCD-grouped M-tile
  const int mTile2 = mt * 256;
  const int nt = (task >> 3) & 3;
  const int nTile = nt * 128;

  const bf16_t* gA = h1 + (size_t)(mTile2 + w * 64 + sRow) * 1024 + sColSwz;
  const bf16_t* gB = W2T + (size_t)(nTile + w * 32 + sRow) * 1024 + sColSwz;
  bf16_t* lA0 = As2 + (w * 64) * 32;
  bf16_t* lB0 = Bs2 + (w * 32) * 32;

  f32x4 acc[4][8];
#pragma unroll
  for (int i = 0; i < 4; ++i)
#pragma unroll
    for (int j = 0; j < 8; ++j) {
      f32x4 z = {0.f, 0.f, 0.f, 0.f};
      acc[i][j] = z;
    }

  // Protect LDS against the previous phase's in-flight readers.
  __syncthreads();

#define STAGE2(buf, k0)                                                     \
  do {                                                                      \
    bf16_t* lA = lA0 + (buf)*8192;                                          \
    bf16_t* lB = lB0 + (buf)*4096;                                          \
    async_load16(gA + (k0), lA);                                            \
    async_load16(gA + (size_t)16 * 1024 + (k0), lA + 16 * 32);              \
    async_load16(gA + (size_t)32 * 1024 + (k0), lA + 32 * 32);              \
    async_load16(gA + (size_t)48 * 1024 + (k0), lA + 48 * 32);              \
    async_load16(gB + (k0), lB);                                            \
    async_load16(gB + (size_t)16 * 1024 + (k0), lB + 16 * 32);              \
  } while (0)

  STAGE2(0, 0);
  __syncthreads();  // prologue drain (vmcnt(0)) + barrier

  int buf = 0;
  for (int k0 = 0; k0 < 1024; k0 += 32) {
    if (k0 + 32 < 1024) STAGE2(buf ^ 1, k0 + 32);  // prefetch next K-tile

    bf16x8 af[4], bfr[8];
#pragma unroll
    for (int t = 0; t < 4; ++t)
      af[t] = *(const bf16x8*)(As2 + buf * 8192 + (w * 64 + t * 16 + l15) * 32 + rchunk8);
#pragma unroll
    for (int t = 0; t < 8; ++t)
      bfr[t] = *(const bf16x8*)(Bs2 + buf * 4096 + (t * 16 + l15) * 32 + rchunk8);
#pragma unroll
    for (int ti = 0; ti < 4; ++ti)
#pragma unroll
      for (int tj = 0; tj < 8; ++tj)
        acc[ti][tj] = __builtin_amdgcn_mfma_f32_16x16x32_bf16(af[ti], bfr[tj], acc[ti][tj], 0, 0, 0);

    if (k0 + 32 < 1024) {
      __syncthreads();  // drains this step's stage (vmcnt) + our ds_reads (lgkm)
      buf ^= 1;
    }
  }
#undef STAGE2

  float sc[8], tc[8], w3c[8];
#pragma unroll
  for (int tj = 0; tj < 8; ++tj) {
    int c = nTile + tj * 16 + l15;
    sc[tj] = s2[c];
    tc[tj] = t2[c];
    w3c[tj] = W3[c];
  }
#pragma unroll
  for (int ti = 0; ti < 4; ++ti)
#pragma unroll
    for (int r = 0; r < 4; ++r) {
      float pv = 0.f;
#pragma unroll
      for (int tj = 0; tj < 8; ++tj) {
        float z = fmaxf(acc[ti][tj][r] * sc[tj] + tc[tj], 0.f);
        pv += z * w3c[tj];
      }
#pragma unroll
      for (int m = 1; m <= 8; m <<= 1) pv += __shfl_xor(pv, m);
      if (l15 == 0)
        partials[(size_t)nt * 65536 + mTile2 + w * 64 + ti * 16 + quad * 4 + r] = pv;
    }
}

// ---- Standalone wrappers (fallback path) ------------------------------------
__global__ __launch_bounds__(256, 2) void gemm1_kernel(
    const float* __restrict__ x, const bf16_t* __restrict__ W1T,
    const float* __restrict__ s1, const float* __restrict__ t1,
    const float* __restrict__ w1last, bf16_t* __restrict__ h1) {
  __shared__ __align__(16) unsigned char smem[81920];
  gemm1_body(x, W1T, s1, t1, w1last, h1, smem, blockIdx.x * 128,
             threadIdx.x & 63, threadIdx.x >> 6);
}

__global__ __launch_bounds__(256, 2) void gemm2_kernel(
    const bf16_t* __restrict__ h1, const bf16_t* __restrict__ W2T,
    const float* __restrict__ s2, const float* __restrict__ t2,
    const float* __restrict__ W3, float* __restrict__ partials) {
  __shared__ __align__(16) unsigned char smem[49152];
  gemm2_task_body(h1, W2T, s2, t2, W3, partials, smem, blockIdx.x,
                  threadIdx.x & 63, threadIdx.x >> 6);
}

__global__ void sigmoid_partials_kernel(const float* __restrict__ partials,
                                        const float* __restrict__ b3,
                                        float* __restrict__ out) {
  int i = blockIdx.x * 256 + threadIdx.x;
  float z = partials[i] + partials[65536 + i] + partials[2 * 65536 + i] +
            partials[3 * 65536 + i] + b3[0];
  out[i] = 1.0f / (1.0f + expf(-z));
}

// ---- Cooperative fused path -------------------------------------------------
__global__ __launch_bounds__(256, 2) void fused_mlp_coop(
    const float* __restrict__ x,
    const bf16_t* __restrict__ W1T, const bf16_t* __restrict__ W2T,
    const float* __restrict__ s1, const float* __restrict__ t1,
    const float* __restrict__ w1last,
    const float* __restrict__ s2, const float* __restrict__ t2,
    const float* __restrict__ W3, const float* __restrict__ b3,
    bf16_t* __restrict__ h1, float* __restrict__ partials,
    float* __restrict__ out) {
  __shared__ __align__(16) unsigned char smem[81920];
  cg::grid_group grid = cg::this_grid();
  const int tid = threadIdx.x;
  const int lane = tid & 63;
  const int w = tid >> 6;

  gemm1_body(x, W1T, s1, t1, w1last, h1, smem, blockIdx.x * 128, lane, w);

  grid.sync();  // h1 visible grid-wide (also block-syncs LDS handoff)

  gemm2_task_body(h1, W2T, s2, t2, W3, partials, smem, blockIdx.x, lane, w);
  gemm2_task_body(h1, W2T, s2, t2, W3, partials, smem, blockIdx.x + 512, lane, w);

  grid.sync();  // partials visible

  if (tid < 128) {
    int r = blockIdx.x * 128 + tid;
    float z = partials[r] + partials[65536 + r] + partials[2 * 65536 + r] +
              partials[3 * 65536 + r] + b3[0];
    out[r] = 1.0f / (1.0f + expf(-z));
  }
}

extern "C" void kernel_launch(void* const* d_in, const int* in_sizes, int n_in,
                              void* d_out, int out_size, void* d_ws, size_t ws_size,
                              hipStream_t stream) {
  const float* x = (const float*)d_in[0];
  const float* W1 = (const float*)d_in[1];
  const float* b1 = (const float*)d_in[2];
  const float* g1 = (const float*)d_in[3];
  const float* be1 = (const float*)d_in[4];
  const float* m1 = (const float*)d_in[5];
  const float* v1 = (const float*)d_in[6];
  const float* W2 = (const float*)d_in[7];
  const float* b2 = (const float*)d_in[8];
  const float* g2 = (const float*)d_in[9];
  const float* be2 = (const float*)d_in[10];
  const float* m2 = (const float*)d_in[11];
  const float* v2 = (const float*)d_in[12];
  const float* W3 = (const float*)d_in[13];
  const float* b3 = (const float*)d_in[14];
  float* out = (float*)d_out;

  char* p = (char*)d_ws;
  bf16_t* h1 = (bf16_t*)p;       p += (size_t)65536 * 1024 * 2;  // 128 MB
  float* partials = (float*)p;   p += (size_t)4 * 65536 * 4;     // 1 MB
  bf16_t* W1T = (bf16_t*)p;      p += (size_t)1024 * 256 * 2;
  bf16_t* W2T = (bf16_t*)p;      p += (size_t)512 * 1024 * 2;
  float* w1last = (float*)p;     p += 1024 * 4;
  float* s1 = (float*)p;         p += 1024 * 4;
  float* t1 = (float*)p;         p += 1024 * 4;
  float* s2 = (float*)p;         p += 512 * 4;
  float* t2 = (float*)p;         p += 512 * 4;

  prep_weights_kernel<<<193, 256, 0, stream>>>(W1, W2, b1, g1, be1, m1, v1,
                                               b2, g2, be2, m2, v2,
                                               W1T, W2T, s1, t1, s2, t2, w1last);

  // Host-side (capture-safe) validation of the cooperative path.
  int dev = 0;
  (void)hipGetDevice(&dev);
  int coopOk = 0;
  (void)hipDeviceGetAttribute(&coopOk, hipDeviceAttributeCooperativeLaunch, dev);
  int numCU = 0;
  (void)hipDeviceGetAttribute(&numCU, hipDeviceAttributeMultiprocessorCount, dev);
  int maxBlk = 0;
  (void)hipOccupancyMaxActiveBlocksPerMultiprocessor(&maxBlk, fused_mlp_coop, 256, 0);

  bool useCoop = (coopOk != 0) && ((long)maxBlk * (long)numCU >= 512L);
  if (useCoop) {
    void* args[] = {(void*)&x, (void*)&W1T, (void*)&W2T, (void*)&s1, (void*)&t1,
                    (void*)&w1last, (void*)&s2, (void*)&t2, (void*)&W3, (void*)&b3,
                    (void*)&h1, (void*)&partials, (void*)&out};
    hipError_t e = hipLaunchCooperativeKernel((const void*)fused_mlp_coop,
                                              dim3(512), dim3(256), args, 0, stream);
    if (e != hipSuccess) useCoop = false;
  }
  if (!useCoop) {
    gemm1_kernel<<<512, 256, 0, stream>>>(x, W1T, s1, t1, w1last, h1);
    gemm2_kernel<<<1024, 256, 0, stream>>>(h1, W2T, s2, t2, W3, partials);
    sigmoid_partials_kernel<<<256, 256, 0, stream>>>(partials, b3, out);
  }
}